// Round 2
// baseline (157.540 us; speedup 1.0000x reference)
//
#include <hip/hip_runtime.h>

#define BB 8
#define NN 2048
#define IND 10
#define QK 32

// Kernel 1: q[b][n][qd] = sum_d s[b,n,d]*Wq[qd,d]; k likewise.
// k stored ev-transposed: kt[b][ev=qd/4][n][qd%4] so kernel 2 reads per-ev
// contiguous float4 runs across columns (perfect coalescing, one float4/col).
__global__ __launch_bounds__(256) void qk_kernel(
    const float* __restrict__ s,
    const float* __restrict__ Wq, const float* __restrict__ Wk,
    float* __restrict__ q_ws, float* __restrict__ kt_ws) {
  int t = blockIdx.x * 256 + threadIdx.x;      // 0 .. B*N*QK-1 (exact)
  int b  = t >> 16;                            // N*QK = 65536
  int n  = (t >> 5) & (NN - 1);
  int qd = t & 31;
  const float* srow = s + (size_t)(b * NN + n) * IND;
  float acq = 0.f, ack = 0.f;
#pragma unroll
  for (int d = 0; d < IND; ++d) {
    float sv = srow[d];
    acq = fmaf(sv, Wq[qd * IND + d], acq);
    ack = fmaf(sv, Wk[qd * IND + d], ack);
  }
  q_ws[(size_t)(b * NN + n) * QK + qd] = acq;
  kt_ws[((size_t)(b * 8 + (qd >> 2)) * NN + n) * 4 + (qd & 3)] = ack;
}

// Kernel 2: one block = (batch, 4 consecutive rows). 256 threads; thread owns
// 8 consecutive cols (tid*8..+7) for all 4 rows. G for those cols is
// prefetched into registers BEFORE the GEMM so HBM latency hides under the
// FMA work; epilogue is register-only math + row reduce + coalesced store.
__global__ __launch_bounds__(256) void attn_kernel(
    const float* __restrict__ G,
    const float* __restrict__ q_ws, const float* __restrict__ kt_ws,
    float* __restrict__ out) {
  const int tid = threadIdx.x;
  const int b = blockIdx.y;
  const int r0 = blockIdx.x * 4;
  const int cbase = tid * 8;

  // ---- G prefetch (issued first; consumed only after the GEMM) ----
  float g[4][8];
#pragma unroll
  for (int r = 0; r < 4; ++r) {
    const float* Grow = G + ((size_t)b * NN + r0 + r) * NN + cbase;
    *(float4*)&g[r][0] = *(const float4*)&Grow[0];
    *(float4*)&g[r][4] = *(const float4*)&Grow[4];
  }

  __shared__ float q_lds[4 * 32];
  __shared__ float red[4][4];
  if (tid < 128)
    q_lds[tid] = q_ws[((size_t)b * NN + r0 + (tid >> 5)) * QK + (tid & 31)];
  __syncthreads();
  __builtin_amdgcn_sched_barrier(0);  // pin G loads above the GEMM

  // ---- GEMM: acc[r][j] = q[r0+r] . k[cbase+j] ----
  float acc[4][8];
#pragma unroll
  for (int r = 0; r < 4; ++r)
#pragma unroll
    for (int j = 0; j < 8; ++j) acc[r][j] = 0.f;

  const float4* kt = (const float4*)kt_ws;  // [b][ev][n] of float4
#pragma unroll
  for (int ev = 0; ev < 8; ++ev) {
    float4 q4[4];
#pragma unroll
    for (int r = 0; r < 4; ++r)
      q4[r] = *(const float4*)&q_lds[r * 32 + ev * 4];  // broadcast read
    const float4* krow = kt + (size_t)(b * 8 + ev) * NN;
#pragma unroll
    for (int j = 0; j < 8; ++j) {
      float4 k4 = krow[cbase + j];
#pragma unroll
      for (int r = 0; r < 4; ++r) {
        acc[r][j] = fmaf(q4[r].x, k4.x, acc[r][j]);
        acc[r][j] = fmaf(q4[r].y, k4.y, acc[r][j]);
        acc[r][j] = fmaf(q4[r].z, k4.z, acc[r][j]);
        acc[r][j] = fmaf(q4[r].w, k4.w, acc[r][j]);
      }
    }
  }

  // ---- v = logits^2 * G (registers), per-thread partial row sums ----
  float rsum[4];
#pragma unroll
  for (int r = 0; r < 4; ++r) {
    float sum = 0.f;
#pragma unroll
    for (int j = 0; j < 8; ++j) {
      float v = acc[r][j];
      v = v * v * g[r][j];
      acc[r][j] = v;
      sum += v;
    }
    rsum[r] = sum;
  }

  // ---- 64-lane butterfly reduce, then 4-wave LDS reduce ----
#pragma unroll
  for (int r = 0; r < 4; ++r) {
    float v = rsum[r];
#pragma unroll
    for (int off = 32; off >= 1; off >>= 1) v += __shfl_xor(v, off, 64);
    rsum[r] = v;
  }
  const int wid = tid >> 6;
  if ((tid & 63) == 0) {
#pragma unroll
    for (int r = 0; r < 4; ++r) red[wid][r] = rsum[r];
  }
  __syncthreads();

  float inv[4];
#pragma unroll
  for (int r = 0; r < 4; ++r) {
    float total = red[0][r] + red[1][r] + red[2][r] + red[3][r];
    inv[r] = 1.0f / (total + 1e-6f);
  }

  // ---- scale + coalesced store ----
#pragma unroll
  for (int r = 0; r < 4; ++r) {
    float* orow = out + ((size_t)b * NN + r0 + r) * NN + cbase;
    float oo[8];
#pragma unroll
    for (int j = 0; j < 8; ++j) oo[j] = acc[r][j] * inv[r];
    *(float4*)&orow[0] = *(const float4*)&oo[0];
    *(float4*)&orow[4] = *(const float4*)&oo[4];
  }
}

extern "C" void kernel_launch(void* const* d_in, const int* in_sizes, int n_in,
                              void* d_out, int out_size, void* d_ws, size_t ws_size,
                              hipStream_t stream) {
  const float* s  = (const float*)d_in[0];
  const float* G  = (const float*)d_in[1];
  const float* Wq = (const float*)d_in[2];
  const float* Wk = (const float*)d_in[3];
  float* out = (float*)d_out;

  float* q_ws  = (float*)d_ws;                       // B*N*QK floats = 2 MB
  float* kt_ws = q_ws + (size_t)BB * NN * QK;        // another 2 MB

  qk_kernel<<<(BB * NN * QK) / 256, 256, 0, stream>>>(s, Wq, Wk, q_ws, kt_ws);

  dim3 grid(NN / 4, BB);
  attn_kernel<<<grid, 256, 0, stream>>>(G, q_ws, kt_ws, out);
}

// Round 3
// 79.458 us; speedup vs baseline: 1.9827x; 1.9827x over previous
//
#include <hip/hip_runtime.h>

#define BB 8
#define NN 2048
#define IND 10
#define QK 32

// Kernel 1: q[b][n][qd] = sum_d s[b,n,d]*Wq[qd,d]; k likewise.
// k stored PERMUTED for kernel 2's exact read pattern:
//   attn thread tid=64*w+i owns cols 8*tid..8*tid+7; per ev it loads 8
//   float4s, j-th at float4-index ((b*4+w)*64 + ev*8+j)*64 + i
//   -> consecutive lanes hit consecutive float4s (perfect coalescing).
// kt2[(b,w)][ev*8+jc][i][c] = k[col=512w+8i+jc][qd=4*ev+c]
__global__ __launch_bounds__(256) void qk_kernel(
    const float* __restrict__ s,
    const float* __restrict__ Wq, const float* __restrict__ Wk,
    float* __restrict__ q_ws, float* __restrict__ kt_ws) {
  int t = blockIdx.x * 256 + threadIdx.x;      // 0 .. B*N*QK-1 (exact)
  int b  = t >> 16;                            // N*QK = 65536
  int n  = (t >> 5) & (NN - 1);
  int qd = t & 31;
  const float* srow = s + (size_t)(b * NN + n) * IND;
  float acq = 0.f, ack = 0.f;
#pragma unroll
  for (int d = 0; d < IND; ++d) {
    float sv = srow[d];
    acq = fmaf(sv, Wq[qd * IND + d], acq);
    ack = fmaf(sv, Wk[qd * IND + d], ack);
  }
  q_ws[(size_t)(b * NN + n) * QK + qd] = acq;
  int w  = n >> 9;          // wave (512 cols each)
  int i  = (n >> 3) & 63;   // lane
  int jc = n & 7;           // col within thread's 8
  int ev = qd >> 2, c = qd & 3;
  kt_ws[((size_t)((b * 4 + w) * 64) + ev * 8 + jc) * 256 + i * 4 + c] = ack;
}

// Kernel 2: one block = (batch, 8 rows). 256 threads; thread owns 8
// consecutive cols. G for those cols is prefetched into registers AFTER the
// q-staging barrier (no vmcnt(0) drain!) and pinned above the GEMM with
// sched_barrier(0) so its HBM latency hides under the ~4096-cy FMA block.
// k loads are lane-coalesced from the permuted kt (L2-resident, 2 MB).
__global__ __launch_bounds__(256, 2) void attn_kernel(
    const float* __restrict__ G,
    const float* __restrict__ q_ws, const float* __restrict__ kt_ws,
    float* __restrict__ out) {
  const int tid = threadIdx.x;
  const int b = blockIdx.y;
  const int r0 = blockIdx.x * 8;
  const int cbase = tid * 8;
  const int w = tid >> 6, lane = tid & 63;

  __shared__ float q_lds[8 * 32];
  __shared__ float red[4][8];
  q_lds[tid] = q_ws[((size_t)b * NN + r0 + (tid >> 5)) * QK + (tid & 31)];
  __syncthreads();

  // ---- G prefetch: issued now, consumed after the GEMM ----
  float g[8][8];
#pragma unroll
  for (int r = 0; r < 8; ++r) {
    const float* Grow = G + ((size_t)b * NN + r0 + r) * NN + cbase;
    *(float4*)&g[r][0] = ((const float4*)Grow)[0];
    *(float4*)&g[r][4] = ((const float4*)Grow)[1];
  }
  __builtin_amdgcn_sched_barrier(0);  // keep G loads above the GEMM

  // ---- GEMM: acc[r][j] = q[r0+r] . k[cbase+j] ----
  float acc[8][8];
#pragma unroll
  for (int r = 0; r < 8; ++r)
#pragma unroll
    for (int j = 0; j < 8; ++j) acc[r][j] = 0.f;

  const float4* kt = (const float4*)kt_ws + ((size_t)(b * 4 + w) * 64) * 64 + lane;
#pragma unroll
  for (int ev = 0; ev < 8; ++ev) {
    float4 q4[8];
#pragma unroll
    for (int r = 0; r < 8; ++r)
      q4[r] = *(const float4*)&q_lds[r * 32 + ev * 4];  // broadcast read
#pragma unroll
    for (int j = 0; j < 8; ++j) {
      float4 k4 = kt[(ev * 8 + j) * 64];  // lane-coalesced
#pragma unroll
      for (int r = 0; r < 8; ++r) {
        acc[r][j] = fmaf(q4[r].x, k4.x, acc[r][j]);
        acc[r][j] = fmaf(q4[r].y, k4.y, acc[r][j]);
        acc[r][j] = fmaf(q4[r].z, k4.z, acc[r][j]);
        acc[r][j] = fmaf(q4[r].w, k4.w, acc[r][j]);
      }
    }
  }

  // ---- v = logits^2 * G (registers), per-thread partial row sums ----
  float rsum[8];
#pragma unroll
  for (int r = 0; r < 8; ++r) {
    float sum = 0.f;
#pragma unroll
    for (int j = 0; j < 8; ++j) {
      float v = acc[r][j];
      v = v * v * g[r][j];
      acc[r][j] = v;
      sum += v;
    }
    rsum[r] = sum;
  }

  // ---- 64-lane butterfly reduce, then 4-wave LDS reduce ----
#pragma unroll
  for (int r = 0; r < 8; ++r) {
    float v = rsum[r];
#pragma unroll
    for (int off = 32; off >= 1; off >>= 1) v += __shfl_xor(v, off, 64);
    rsum[r] = v;
  }
  if ((tid & 63) == 0) {
#pragma unroll
    for (int r = 0; r < 8; ++r) red[w][r] = rsum[r];
  }
  __syncthreads();

  float inv[8];
#pragma unroll
  for (int r = 0; r < 8; ++r) {
    float total = red[0][r] + red[1][r] + red[2][r] + red[3][r];
    inv[r] = 1.0f / (total + 1e-6f);
  }

  // ---- scale + coalesced store ----
#pragma unroll
  for (int r = 0; r < 8; ++r) {
    float* orow = out + ((size_t)b * NN + r0 + r) * NN + cbase;
    float oo[8];
#pragma unroll
    for (int j = 0; j < 8; ++j) oo[j] = acc[r][j] * inv[r];
    *(float4*)&orow[0] = *(const float4*)&oo[0];
    *(float4*)&orow[4] = *(const float4*)&oo[4];
  }
}

extern "C" void kernel_launch(void* const* d_in, const int* in_sizes, int n_in,
                              void* d_out, int out_size, void* d_ws, size_t ws_size,
                              hipStream_t stream) {
  const float* s  = (const float*)d_in[0];
  const float* G  = (const float*)d_in[1];
  const float* Wq = (const float*)d_in[2];
  const float* Wk = (const float*)d_in[3];
  float* out = (float*)d_out;

  float* q_ws  = (float*)d_ws;                       // B*N*QK floats = 2 MB
  float* kt_ws = q_ws + (size_t)BB * NN * QK;        // another 2 MB

  qk_kernel<<<(BB * NN * QK) / 256, 256, 0, stream>>>(s, Wq, Wk, q_ws, kt_ws);

  dim3 grid(NN / 8, BB);
  attn_kernel<<<grid, 256, 0, stream>>>(G, q_ws, kt_ws, out);
}